// Round 1
// baseline (234.705 us; speedup 1.0000x reference)
//
#include <hip/hip_runtime.h>

typedef __bf16 v8bf __attribute__((ext_vector_type(8)));
typedef float f32x4 __attribute__((ext_vector_type(4)));
typedef unsigned short u16x8 __attribute__((ext_vector_type(8)));

#define SLEN 256
#define BATCH 256
#define DIM 512
#define SCALE 0.044194173824159216f  // sqrt(1/512)
#define TS 64                         // token tile (s-rows per block, fixed b)
#define LDX 520                       // padded bf16 row stride for X/Z tiles
#define LDB 72                        // padded bf16 row stride for B tiles
#define KC 64                         // K-chunk staged for B

#define MFMA(a, b, c) __builtin_amdgcn_mfma_f32_16x16x32_bf16((a), (b), (c), 0, 0, 0)

__device__ __forceinline__ unsigned short f2bf(float f) {
  union { float f; unsigned int u; } v; v.f = f;
  unsigned int r = v.u + 0x7FFFu + ((v.u >> 16) & 1u);  // RNE
  return (unsigned short)(r >> 16);
}
__device__ __forceinline__ float bf2f(unsigned short u) {
  union { unsigned int u; float f; } v; v.u = ((unsigned int)u) << 16;
  return v.f;
}
__device__ __forceinline__ v8bf ld8(const unsigned short* p) {
  u16x8 t = *reinterpret_cast<const u16x8*>(p);
  return __builtin_bit_cast(v8bf, t);
}

// ---------- prep: Mt[e][d] = sum_f Wk[f,e]*Wq[f,d]  (= (Wq^T Wk)^T, bf16) ----------
__global__ __launch_bounds__(256) void prep_mt(const float* __restrict__ Wq,
                                               const float* __restrict__ Wk,
                                               unsigned short* __restrict__ Mt) {
  __shared__ float As[32][33];
  __shared__ float Bs[32][33];
  const int e0 = (blockIdx.x & 15) * 32;
  const int d0 = (blockIdx.x >> 4) * 32;
  const int tid = threadIdx.x;
  const int tm = (tid & 15) * 2;
  const int tn = (tid >> 4) * 2;
  const int lf = tid >> 3;
  const int lc = (tid & 7) * 4;
  float a00 = 0.f, a01 = 0.f, a10 = 0.f, a11 = 0.f;
  for (int f0 = 0; f0 < DIM; f0 += 32) {
    __syncthreads();
    const float4 a = *reinterpret_cast<const float4*>(Wk + (size_t)(f0 + lf) * DIM + e0 + lc);
    const float4 b = *reinterpret_cast<const float4*>(Wq + (size_t)(f0 + lf) * DIM + d0 + lc);
    As[lf][lc] = a.x; As[lf][lc + 1] = a.y; As[lf][lc + 2] = a.z; As[lf][lc + 3] = a.w;
    Bs[lf][lc] = b.x; Bs[lf][lc + 1] = b.y; Bs[lf][lc + 2] = b.z; Bs[lf][lc + 3] = b.w;
    __syncthreads();
#pragma unroll
    for (int k = 0; k < 32; ++k) {
      const float x0 = As[k][tm], x1 = As[k][tm + 1];
      const float y0 = Bs[k][tn], y1 = Bs[k][tn + 1];
      a00 += x0 * y0; a01 += x0 * y1; a10 += x1 * y0; a11 += x1 * y1;
    }
  }
  Mt[(size_t)(e0 + tm) * DIM + d0 + tn] = f2bf(a00);
  Mt[(size_t)(e0 + tm) * DIM + d0 + tn + 1] = f2bf(a01);
  Mt[(size_t)(e0 + tm + 1) * DIM + d0 + tn] = f2bf(a10);
  Mt[(size_t)(e0 + tm + 1) * DIM + d0 + tn + 1] = f2bf(a11);
}

// ---------- prep: Wv fp32 -> bf16 ----------
__global__ __launch_bounds__(256) void conv_wv(const float* __restrict__ Wv,
                                               unsigned short* __restrict__ Wvb) {
  const int idx = (blockIdx.x * 256 + threadIdx.x) * 4;
  const float4 v = *reinterpret_cast<const float4*>(Wv + idx);
  uint2 p;
  p.x = (unsigned int)f2bf(v.x) | ((unsigned int)f2bf(v.y) << 16);
  p.y = (unsigned int)f2bf(v.z) | ((unsigned int)f2bf(v.w) << 16);
  *reinterpret_cast<uint2*>(Wvb + idx) = p;
}

// ---------- prep: wkr[d] = sum_f Wk[f,d]*rq[f] ----------
__global__ __launch_bounds__(256) void wkr_k(const float* __restrict__ Wk,
                                             const float* __restrict__ rq,
                                             float* __restrict__ wkr) {
  const int f0 = blockIdx.x * 16;
  const int d = threadIdx.x;
  float s1 = 0.f, s2 = 0.f;
#pragma unroll 4
  for (int f = f0; f < f0 + 16; ++f) {
    const float r = rq[f];
    s1 += Wk[(size_t)f * DIM + d] * r;
    s2 += Wk[(size_t)f * DIM + d + 256] * r;
  }
  atomicAdd(&wkr[d], s1);
  atomicAdd(&wkr[d + 256], s2);
}

// ---------- pass1: d_t = x^T Mt^T x + wkr.x  -> rd; per-batch R, xsum, xw ----------
__global__ __launch_bounds__(256, 2) void pass1(
    const float* __restrict__ X, const unsigned short* __restrict__ Mt,
    const float* __restrict__ wkr, float* __restrict__ rd_out,
    float* __restrict__ Rsum, float* __restrict__ xsum, float* __restrict__ xw) {
  __shared__ __align__(16) unsigned short Xs[TS * LDX];
  __shared__ __align__(16) unsigned short Bsh[64 * LDB];
  __shared__ float wkrs[DIM];
  __shared__ float dacc[TS];
  __shared__ float rds[TS];

  const int tid = threadIdx.x;
  const int b = blockIdx.x & 255;
  const int s0 = (blockIdx.x >> 8) * TS;
  const int lane = tid & 63;
  const int wave = tid >> 6;
  const int wr = wave >> 1, wc = wave & 1;
  const int g = lane >> 4, c = lane & 15;

  // stage X tile: rows are s0..s0+63 at fixed batch b
#pragma unroll 4
  for (int r = 0; r < TS; ++r) {
    const float2 v = *reinterpret_cast<const float2*>(
        X + ((size_t)(s0 + r) * BATCH + b) * DIM + tid * 2);
    Xs[r * LDX + tid * 2] = f2bf(v.x);
    Xs[r * LDX + tid * 2 + 1] = f2bf(v.y);
  }
  wkrs[tid] = wkr[tid];
  wkrs[tid + 256] = wkr[tid + 256];
  if (tid < TS) dacc[tid] = 0.f;

  float dp0[4] = {0.f, 0.f, 0.f, 0.f};
  float dp1[4] = {0.f, 0.f, 0.f, 0.f};

  for (int et = 0; et < 8; ++et) {
    const int e0 = et * 64;
    f32x4 acc00 = {0.f, 0.f, 0.f, 0.f}, acc01 = {0.f, 0.f, 0.f, 0.f};
    f32x4 acc10 = {0.f, 0.f, 0.f, 0.f}, acc11 = {0.f, 0.f, 0.f, 0.f};
    for (int kc0 = 0; kc0 < DIM; kc0 += KC) {
      __syncthreads();  // protect previous B reads
      {
        const int e = tid >> 2;
        const int kq = (tid & 3) * 16;
        const uint4* src = reinterpret_cast<const uint4*>(Mt + (size_t)(e0 + e) * DIM + kc0 + kq);
        const uint4 w0 = src[0];
        const uint4 w1 = src[1];
        *reinterpret_cast<uint4*>(&Bsh[e * LDB + kq]) = w0;
        *reinterpret_cast<uint4*>(&Bsh[e * LDB + kq + 8]) = w1;
      }
      __syncthreads();
#pragma unroll
      for (int ks = 0; ks < KC; ks += 32) {
        const int ka = kc0 + ks + 8 * g;
        const int kb = ks + 8 * g;
        const v8bf fa0 = ld8(&Xs[(32 * wr + c) * LDX + ka]);
        const v8bf fa1 = ld8(&Xs[(32 * wr + 16 + c) * LDX + ka]);
        const v8bf fb0 = ld8(&Bsh[(32 * wc + c) * LDB + kb]);
        const v8bf fb1 = ld8(&Bsh[(32 * wc + 16 + c) * LDB + kb]);
        acc00 = MFMA(fa0, fb0, acc00);
        acc01 = MFMA(fa0, fb1, acc01);
        acc10 = MFMA(fa1, fb0, acc10);
        acc11 = MFMA(fa1, fb1, acc11);
      }
    }
    // epilogue: d_t += (u + wkr) . x  over this e-tile
#pragma unroll
    for (int i = 0; i < 4; ++i) {
      const int r0 = 32 * wr + 4 * g + i;
      const int ec0 = e0 + 32 * wc + c;
      const float w0 = wkrs[ec0], w1 = wkrs[ec0 + 16];
      dp0[i] += (acc00[i] + w0) * bf2f(Xs[r0 * LDX + ec0]) +
                (acc01[i] + w1) * bf2f(Xs[r0 * LDX + ec0 + 16]);
      dp1[i] += (acc10[i] + w0) * bf2f(Xs[(r0 + 16) * LDX + ec0]) +
                (acc11[i] + w1) * bf2f(Xs[(r0 + 16) * LDX + ec0 + 16]);
    }
  }

  // reduce across the 16 column-lanes, then combine wc halves via LDS atomics
#pragma unroll
  for (int i = 0; i < 4; ++i) {
    float v0 = dp0[i], v1 = dp1[i];
    v0 += __shfl_xor(v0, 1); v0 += __shfl_xor(v0, 2);
    v0 += __shfl_xor(v0, 4); v0 += __shfl_xor(v0, 8);
    v1 += __shfl_xor(v1, 1); v1 += __shfl_xor(v1, 2);
    v1 += __shfl_xor(v1, 4); v1 += __shfl_xor(v1, 8);
    if (c == 0) {
      atomicAdd(&dacc[32 * wr + 4 * g + i], v0);
      atomicAdd(&dacc[32 * wr + 16 + 4 * g + i], v1);
    }
  }
  __syncthreads();

  if (tid < TS) {
    float sc = dacc[tid] * SCALE;
    sc = fminf(fmaxf(sc, -5.0f), 7.0f);
    const float r = expf(sc);
    rds[tid] = r;
    rd_out[(size_t)b * SLEN + s0 + tid] = r;
    float t = r;
    t += __shfl_xor(t, 1); t += __shfl_xor(t, 2); t += __shfl_xor(t, 4);
    t += __shfl_xor(t, 8); t += __shfl_xor(t, 16); t += __shfl_xor(t, 32);
    if (tid == 0) atomicAdd(&Rsum[b], t);
  }
  __syncthreads();

  // per-batch xsum / xw partials from the staged tile
#pragma unroll
  for (int dd = 0; dd < 2; ++dd) {
    const int d = tid + dd * 256;
    float s1 = 0.f, s2 = 0.f;
    for (int r = 0; r < TS; ++r) {
      const float xv = bf2f(Xs[r * LDX + d]);
      s1 += xv;
      s2 += rds[r] * xv;
    }
    atomicAdd(&xsum[(size_t)b * DIM + d], s1);
    atomicAdd(&xw[(size_t)b * DIM + d], s2);
  }
}

// ---------- pass2: out = Z @ Wv^T, Z built on the fly ----------
__global__ __launch_bounds__(256, 2) void pass2(
    const float* __restrict__ X, const unsigned short* __restrict__ Wvb,
    const float* __restrict__ rd, const float* __restrict__ Rsum,
    const float* __restrict__ xsum, const float* __restrict__ xw,
    float* __restrict__ out) {
  __shared__ __align__(16) unsigned short Zs[TS * LDX];
  __shared__ __align__(16) unsigned short Bsh[64 * LDB];
  __shared__ float xss[DIM];
  __shared__ float xws[DIM];
  __shared__ float rds[TS];

  const int tid = threadIdx.x;
  const int b = blockIdx.x & 255;
  const int s0 = (blockIdx.x >> 8) * TS;
  const int lane = tid & 63;
  const int wave = tid >> 6;
  const int wr = wave >> 1, wc = wave & 1;
  const int g = lane >> 4, c = lane & 15;

  xss[tid] = xsum[(size_t)b * DIM + tid];
  xss[tid + 256] = xsum[(size_t)b * DIM + tid + 256];
  xws[tid] = xw[(size_t)b * DIM + tid];
  xws[tid + 256] = xw[(size_t)b * DIM + tid + 256];
  if (tid < TS) rds[tid] = rd[(size_t)b * SLEN + s0 + tid];
  const float Rb = Rsum[b];
  const float invR = 1.0f / Rb;
  const float gam = invR * (1.0f / 256.0f);
  __syncthreads();

  // stage Z tile: z = (rd/R - 1/s)*x + ((1 - rd/R)/s)*xsum + (1/(sR))*xw
#pragma unroll 4
  for (int r = 0; r < TS; ++r) {
    const float rv = rds[r];
    const float al = rv * invR - (1.0f / 256.0f);
    const float be = (1.0f - rv * invR) * (1.0f / 256.0f);
    const float2 v = *reinterpret_cast<const float2*>(
        X + ((size_t)(s0 + r) * BATCH + b) * DIM + tid * 2);
    const int d0 = tid * 2;
    Zs[r * LDX + d0] = f2bf(al * v.x + be * xss[d0] + gam * xws[d0]);
    Zs[r * LDX + d0 + 1] = f2bf(al * v.y + be * xss[d0 + 1] + gam * xws[d0 + 1]);
  }

  const size_t outbase = ((size_t)b * SLEN + s0) * DIM;
  for (int et = 0; et < 8; ++et) {
    const int e0 = et * 64;
    f32x4 acc00 = {0.f, 0.f, 0.f, 0.f}, acc01 = {0.f, 0.f, 0.f, 0.f};
    f32x4 acc10 = {0.f, 0.f, 0.f, 0.f}, acc11 = {0.f, 0.f, 0.f, 0.f};
    for (int kc0 = 0; kc0 < DIM; kc0 += KC) {
      __syncthreads();
      {
        const int e = tid >> 2;
        const int kq = (tid & 3) * 16;
        const uint4* src = reinterpret_cast<const uint4*>(Wvb + (size_t)(e0 + e) * DIM + kc0 + kq);
        const uint4 w0 = src[0];
        const uint4 w1 = src[1];
        *reinterpret_cast<uint4*>(&Bsh[e * LDB + kq]) = w0;
        *reinterpret_cast<uint4*>(&Bsh[e * LDB + kq + 8]) = w1;
      }
      __syncthreads();
#pragma unroll
      for (int ks = 0; ks < KC; ks += 32) {
        const int ka = kc0 + ks + 8 * g;
        const int kb = ks + 8 * g;
        const v8bf fa0 = ld8(&Zs[(32 * wr + c) * LDX + ka]);
        const v8bf fa1 = ld8(&Zs[(32 * wr + 16 + c) * LDX + ka]);
        const v8bf fb0 = ld8(&Bsh[(32 * wc + c) * LDB + kb]);
        const v8bf fb1 = ld8(&Bsh[(32 * wc + 16 + c) * LDB + kb]);
        acc00 = MFMA(fa0, fb0, acc00);
        acc01 = MFMA(fa0, fb1, acc01);
        acc10 = MFMA(fa1, fb0, acc10);
        acc11 = MFMA(fa1, fb1, acc11);
      }
    }
#pragma unroll
    for (int i = 0; i < 4; ++i) {
      const int r0 = 32 * wr + 4 * g + i;
      const int c0 = e0 + 32 * wc + c;
      out[outbase + (size_t)r0 * DIM + c0] = acc00[i];
      out[outbase + (size_t)r0 * DIM + c0 + 16] = acc01[i];
      out[outbase + (size_t)(r0 + 16) * DIM + c0] = acc10[i];
      out[outbase + (size_t)(r0 + 16) * DIM + c0 + 16] = acc11[i];
    }
  }
}

extern "C" void kernel_launch(void* const* d_in, const int* in_sizes, int n_in,
                              void* d_out, int out_size, void* d_ws, size_t ws_size,
                              hipStream_t stream) {
  (void)in_sizes; (void)n_in; (void)out_size; (void)ws_size;
  const float* X = (const float*)d_in[0];
  const float* Wq = (const float*)d_in[1];
  const float* Wk = (const float*)d_in[2];
  const float* Wv = (const float*)d_in[3];
  const float* rq = (const float*)d_in[4];
  float* out = (float*)d_out;

  char* ws = (char*)d_ws;
  unsigned short* Mt = (unsigned short*)(ws + 0);        // 512 KB bf16
  unsigned short* Wvb = (unsigned short*)(ws + 524288);  // 512 KB bf16
  float* rd = (float*)(ws + 1048576);                    // 256 KB
  float* wkr = (float*)(ws + 1310720);                   // 2 KB   (zeroed)
  float* Rsum = (float*)(ws + 1312768);                  // 1 KB   (zeroed)
  float* xsum = (float*)(ws + 1313792);                  // 512 KB (zeroed)
  float* xw = (float*)(ws + 1838080);                    // 512 KB (zeroed)

  hipMemsetAsync(ws + 1310720, 0, 1051648, stream);  // wkr..xw contiguous

  prep_mt<<<dim3(256), dim3(256), 0, stream>>>(Wq, Wk, Mt);
  conv_wv<<<dim3(256), dim3(256), 0, stream>>>(Wv, Wvb);
  wkr_k<<<dim3(32), dim3(256), 0, stream>>>(Wk, rq, wkr);
  pass1<<<dim3(1024), dim3(256), 0, stream>>>(X, Mt, wkr, rd, Rsum, xsum, xw);
  pass2<<<dim3(1024), dim3(256), 0, stream>>>(X, Wvb, rd, Rsum, xsum, xw, out);
}